// Round 9
// baseline (30.957 us; speedup 1.0000x reference)
//
#include <hip/hip_runtime.h>

// Bezier2Image, single-dispatch fused kernel:
//   res[b,w,v] = min(1, sum_k gX[b,w,k]*gY[b,v,k]),  k = (curve, sample)
// Grid = 256 blocks = 128 batches x 2 v-halves (output split -> no cross-block
// reduction, no workspace, ONE kernel launch). Block = 512 thr = 8 waves.
// Each wave owns 20 curves (disjoint K-slice) + a private 6KB LDS slice and
// stages truncated 8px gaussian windows DIRECTLY in mfma_f32_32x32x16_f16
// fragment layout (barrier-free main loop; R7-proven compiler fences).
// Regions (512 f16 = 1KB each) within a wave slice:
//   0..3: gX  (rowhalf*2 + kstep)   rows w 0..63 (60 used)
//   4..5: gY  (kstep)               rows v_local 0..31 (30 used, this half)
// elem addr: region*512 + ((n>>3)&1)*256 + (row&31)*8 + (n&7)   [n = sample]
// Fragment read: lane reads 8 f16 at wsh + region*512 + lane*8 (linear,
// conflict-free). Window exps are incremental: e_i = E0 * R^i * C_i with
// C_i = 2^(-K2*i^2) constant table -> 2 exps per column instead of 8
// (exp2 via __builtin_amdgcn_exp2f; __exp2f does not exist in HIP).
// Epilogue: 3 barriers, LDS tree-reduce 8 wave accs (4 slots 64x32 f32),
// clamp, store straight to out.

namespace {
constexpr int   kN = 30;              // samples per curve
constexpr int   kW = 60;              // image side
constexpr int   kL = 160;             // curves per batch
constexpr int   kB = 128;             // batch
constexpr float kRadPix = 3.5f;       // truncation radius in pixels
constexpr float kK2 = 2.0036847f;     // 5000/60^2 * log2(e)  (exp2 scale, px units)
constexpr int   kPix = kW * kW;       // 3600
constexpr int   CPW = 20;             // curves per wave (160 / 8 waves)
}

using f32x16 = __attribute__((ext_vector_type(16))) float;
using f16x8  = __attribute__((ext_vector_type(8))) _Float16;

#define LDS_FENCE() asm volatile("" ::: "memory")

__global__ __launch_bounds__(512, 2) void bezier_fused_kernel(const float* __restrict__ x,
                                                              float* __restrict__ out) {
  __shared__ _Float16 sh[8 * 3072];   // 48 KB: 8 waves x 6KB private staging
  const int b    = blockIdx.x >> 1;
  const int vh   = blockIdx.x & 1;    // v-half: columns [vh*30, vh*30+30)
  const int tid  = threadIdx.x;
  const int lane = tid & 63;
  const int wid  = tid >> 6;
  const int l31  = lane & 31;
  const int hi   = lane >> 5;

  _Float16* wsh = sh + wid * 3072;    // wave-private slice

  // ---- fixed staging role: mat = lane>>5 (0=gX rows w, 1=gY rows v), n = lane&31
  const int mat = hi;
  const int n   = l31;                // sample index; 30,31 = zero pad
  const bool valid = (n < kN);
  const int kstep = n >> 4;
  const int colbase = (mat ? 2048 : 0) + kstep * 512 + ((n >> 3) & 1) * 256 + (n & 7);
  const int mlo = mat ? vh * 30 : 0;  // staging row range [mlo, mhi)
  const int mhi = mlo + (mat ? 30 : 60);

  // constant Bernstein basis for this thread's sample
  float B0, B1, B2, B3;
  {
    float t0 = (float)n * (1.0f / 30.0f);
    float t  = 2.0f * t0 * t0 * t0 - 3.0f * t0 * t0 + 2.0f * t0;
    float t2 = t * t, t3 = t2 * t;
    B0 = t3;
    B1 = 3.0f * (t2 - t3);
    B2 = 3.0f * (t3 - 2.0f * t2 + t);
    float omt = 1.0f - t;
    B3 = omt * omt * omt;
  }

  // gaussian tail table C_i = 2^(-K2*i*i)
  const float C1 = 0.24943437f, C2 = 3.8707470e-3f, C3 = 3.7368678e-6f,
              C4 = 2.2444484e-10f, C5 = 8.3867112e-16f, C6 = 1.9498895e-22f,
              C7 = 2.8205783e-30f;

  // init-zero own wave slice (6KB = 6 x b128 per lane), no barrier needed
  {
    uint4* z = (uint4*)wsh;
#pragma unroll
    for (int i = 0; i < 6; ++i) z[lane + i * 64] = make_uint4(0, 0, 0, 0);
  }
  LDS_FENCE();

  f32x16 acc0 = {}, acc1 = {};        // w-rows 0-31 / 32-63, v-cols this half
  const float* xb = x + ((size_t)b * kL + (size_t)wid * CPW) * 8;
  const _Float16* rbase = wsh + lane * 8;

  int lo_prev = -1000;
  for (int st = 0; st < CPW; ++st) {
    LDS_FENCE();                      // WAR: prev-iter frag reads before stores
    if (valid) {
      const float4* c = (const float4*)(xb + st * 8);
      float4 c0 = c[0], c1 = c[1];
      float P = mat ? (B0 * c0.y + B1 * c0.w + B2 * c1.y + B3 * c1.w)
                    : (B0 * c0.x + B1 * c0.z + B2 * c1.x + B3 * c1.z);
      float fp = P * 60.0f;           // pixel-space center
      int lo = (int)ceilf(fp - kRadPix);
#pragma unroll
      for (int i = 0; i < 8; ++i) {   // zero previous window
        int m = lo_prev + i;
        if (m >= mlo && m < mhi) {
          int ro = mat ? ((m - mlo) << 3) : (((m >> 5) << 10) + ((m & 31) << 3));
          wsh[colbase + ro] = (_Float16)0.0f;
        }
      }
      // incremental gaussian: e_i = E0 * R^i * C_i = 2^(-K2*(u+i)^2)
      float u  = (float)lo - fp;      // in (-3.5, -2.5]
      float E0 = __builtin_amdgcn_exp2f(-kK2 * u * u);
      float R  = __builtin_amdgcn_exp2f(-2.0f * kK2 * u);
      float p1 = E0 * R, p2 = p1 * R, p3 = p2 * R, p4 = p3 * R,
            p5 = p4 * R, p6 = p5 * R, p7 = p6 * R;
      float e[8] = {E0, p1 * C1, p2 * C2, p3 * C3, p4 * C4, p5 * C5, p6 * C6, p7 * C7};
#pragma unroll
      for (int i = 0; i < 8; ++i) {   // write new window
        int m = lo + i;
        if (m >= mlo && m < mhi) {
          int ro = mat ? ((m - mlo) << 3) : (((m >> 5) << 10) + ((m & 31) << 3));
          wsh[colbase + ro] = (_Float16)e[i];
        }
      }
      lo_prev = lo;
    }
    LDS_FENCE();                      // RAW: stores before this iter's frag reads

    // ---- fragment reads (linear, conflict-free) + 4 MFMA
    f16x8 a0k0 = *(const f16x8*)(rbase + 0 * 512);
    f16x8 a0k1 = *(const f16x8*)(rbase + 1 * 512);
    f16x8 a1k0 = *(const f16x8*)(rbase + 2 * 512);
    f16x8 a1k1 = *(const f16x8*)(rbase + 3 * 512);
    f16x8 bk0  = *(const f16x8*)(rbase + 4 * 512);
    f16x8 bk1  = *(const f16x8*)(rbase + 5 * 512);
    acc0 = __builtin_amdgcn_mfma_f32_32x32x16_f16(a0k0, bk0, acc0, 0, 0, 0);
    acc1 = __builtin_amdgcn_mfma_f32_32x32x16_f16(a1k0, bk0, acc1, 0, 0, 0);
    acc0 = __builtin_amdgcn_mfma_f32_32x32x16_f16(a0k1, bk1, acc0, 0, 0, 0);
    acc1 = __builtin_amdgcn_mfma_f32_32x32x16_f16(a1k1, bk1, acc1, 0, 0, 0);
  }

  // ---- epilogue: tree-reduce 8 wave accs in reused LDS (4 slots of 64x32 f32)
  __syncthreads();                    // all waves done with staging LDS
  float* red = (float*)sh;            // 4 slots x 2048 f32 = 32 KB
  if (wid < 4) {
    float* slot = red + wid * 2048;
#pragma unroll
    for (int r = 0; r < 16; ++r) {
      int row = (r & 3) + 8 * (r >> 2) + 4 * hi;
      slot[row * 32 + l31]        = acc0[r];
      slot[(row + 32) * 32 + l31] = acc1[r];
    }
  }
  __syncthreads();
  if (wid >= 4) {
    float* slot = red + (wid - 4) * 2048;
#pragma unroll
    for (int r = 0; r < 16; ++r) {
      int row = (r & 3) + 8 * (r >> 2) + 4 * hi;
      slot[row * 32 + l31]        += acc0[r];
      slot[(row + 32) * 32 + l31] += acc1[r];
    }
  }
  __syncthreads();

  float* ob = out + (size_t)b * kPix + vh * 30;
  for (int p = tid; p < kW * 30; p += 512) {
    int w  = p / 30;
    int vl = p - w * 30;
    int idx = w * 32 + vl;
    float s = red[idx] + red[2048 + idx] + red[4096 + idx] + red[6144 + idx];
    ob[w * kW + vl] = fminf(s, 1.0f);
  }
}

extern "C" void kernel_launch(void* const* d_in, const int* in_sizes, int n_in,
                              void* d_out, int out_size, void* d_ws, size_t ws_size,
                              hipStream_t stream) {
  const float* x = (const float*)d_in[0];
  float* out = (float*)d_out;
  bezier_fused_kernel<<<dim3(kB * 2), dim3(512), 0, stream>>>(x, out);
}

// Round 10
// 25.508 us; speedup vs baseline: 1.2136x; 1.2136x over previous
//
#include <hip/hip_runtime.h>

// Bezier2Image via separable GEMM on matrix cores (R3 structure + latency cuts):
//   res[b,w,v] = sum_k gX[b,w,k] * gY[b,v,k],  k = (curve, sample)
// Grid = 128 batches x KSPLIT(8) blocks, 256 thr (4 waves). Per 128-col chunk:
// scatter truncated 8px gaussian windows (f16, padded rows) -> barrier ->
// 16x16x32 MFMA, each wave owns a 32x32 C-quadrant -> barrier. Ctrl points
// for chunk ch+1 are prefetched before chunk ch's scatter (global latency
// hidden under scatter+MFMA). Partials plain-stored; reduce sums 8 + clamps.

namespace {
constexpr int   kN = 30;            // samples per curve
constexpr int   kW = 60;            // image side
constexpr int   kL = 160;           // curves per batch
constexpr int   kB = 128;           // batch
constexpr float kAlphaInv = 5000.0f;  // 1/2e-4
constexpr float kRadPix = 3.5f;     // truncation radius in pixels
constexpr int   KSPLIT = 8;         // K-split blocks per batch
constexpr int   CPB = kL / KSPLIT;  // 20 curves per block
constexpr int   KC = 128;           // k-chunk (4 curves x 32, 30 used)
constexpr int   NCH = CPB * 32 / KC;  // 5 chunks
constexpr int   LDK = KC + 8;       // padded LDS row length (f16)
constexpr int   kPix = kW * kW;     // 3600
}

using f32x4 = __attribute__((ext_vector_type(4))) float;
using f16x8 = __attribute__((ext_vector_type(8))) _Float16;

__global__ __launch_bounds__(256, 4) void bezier_gemm_kernel(const float* __restrict__ x,
                                                             float* __restrict__ partial) {
  __shared__ _Float16 sh[2][64][LDK];   // 34.8 KB
  const int b    = blockIdx.x / KSPLIT;
  const int ks   = blockIdx.x % KSPLIT;
  const int tid  = threadIdx.x;
  const int lane = tid & 63;
  const int wid  = tid >> 6;
  const int wi = wid >> 1;              // wave row-half of C
  const int vi = wid & 1;               // wave col-half of C
  const int l15 = lane & 15;
  const int l4  = lane >> 4;

  f32x4 acc4[2][2] = {};                // 2x2 tiles of 16x16, fp32

  const float* xb = x + ((size_t)b * kL + (size_t)ks * CPB) * 8;

  // ---- initial full zero of the staging tile ----
  {
    uint4* shv = (uint4*)&sh[0][0][0];
    constexpr int NZ = 2 * 64 * LDK * 2 / 16;
    for (int i = tid; i < NZ; i += 256) shv[i] = make_uint4(0, 0, 0, 0);
  }

  // ---- per-thread fixed staging role: one (matrix, column) ----
  const int col = tid & 127;            // k-column within chunk (constant)
  const int mat = tid >> 7;             // 0 = gX, 1 = gY       (constant)
  const int n   = col & 31;             // sample index (constant; 30,31 = pad)
  const bool valid = (n < kN);
  float B0, B1, B2, B3;
  {
    float t0 = (float)n * (1.0f / 30.0f);
    float t  = 2.0f * t0 * t0 * t0 - 3.0f * t0 * t0 + 2.0f * t0;
    float t2 = t * t, t3 = t2 * t;
    B0 = t3;
    B1 = 3.0f * (t2 - t3);
    B2 = 3.0f * (t3 - 2.0f * t2 + t);
    float omt = 1.0f - t;
    B3 = omt * omt * omt;
  }
  int lo_prev = 0;                      // rows 0..7 start zeroed; re-zero harmless

  // prefetch ctrl points for chunk 0
  const float4* cp = (const float4*)(xb + (col >> 5) * 8);
  float4 pc0 = cp[0], pc1 = cp[1];

  __syncthreads();                      // initial zero visible to all

  for (int ch = 0; ch < NCH; ++ch) {
    // ---- issue next chunk's ctrl-point loads early (hidden under this chunk)
    float4 nc0, nc1;
    if (ch + 1 < NCH) {
      const float4* np = (const float4*)(xb + ((ch + 1) * 4 + (col >> 5)) * 8);
      nc0 = np[0];
      nc1 = np[1];
    }

    // ---- scatter: zero own old window, write own new window (column-exclusive)
    if (valid) {
      float P = mat ? (B0 * pc0.y + B1 * pc0.w + B2 * pc1.y + B3 * pc1.w)
                    : (B0 * pc0.x + B1 * pc0.z + B2 * pc1.x + B3 * pc1.z);
      float fp = P * (float)kW;
      int lo = (int)ceilf(fp - kRadPix);
#pragma unroll
      for (int i = 0; i < 8; ++i) {
        int m = lo_prev + i;
        if (m >= 0 && m < kW) sh[mat][m][col] = (_Float16)0.0f;
      }
#pragma unroll
      for (int i = 0; i < 8; ++i) {
        int m = lo + i;
        if (m >= 0 && m < kW) {
          float d = (float)m * (1.0f / 60.0f) - P;
          sh[mat][m][col] = (_Float16)__expf(-d * d * kAlphaInv);
        }
      }
      lo_prev = lo;
    }
    __syncthreads();

    // ---- MFMA over chunk: wave (wi,vi) owns C[wi*32..+32][vi*32..+32] ----
#pragma unroll
    for (int kk = 0; kk < KC; kk += 32) {
      const int ke = kk + l4 * 8;
      f16x8 a0 = *(const f16x8*)&sh[0][wi * 32 + l15][ke];
      f16x8 a1 = *(const f16x8*)&sh[0][wi * 32 + 16 + l15][ke];
      f16x8 b0 = *(const f16x8*)&sh[1][vi * 32 + l15][ke];
      f16x8 b1 = *(const f16x8*)&sh[1][vi * 32 + 16 + l15][ke];
      acc4[0][0] = __builtin_amdgcn_mfma_f32_16x16x32_f16(a0, b0, acc4[0][0], 0, 0, 0);
      acc4[0][1] = __builtin_amdgcn_mfma_f32_16x16x32_f16(a0, b1, acc4[0][1], 0, 0, 0);
      acc4[1][0] = __builtin_amdgcn_mfma_f32_16x16x32_f16(a1, b0, acc4[1][0], 0, 0, 0);
      acc4[1][1] = __builtin_amdgcn_mfma_f32_16x16x32_f16(a1, b1, acc4[1][1], 0, 0, 0);
    }
    __syncthreads();   // MFMA reads done before next chunk's scatter overwrites

    pc0 = nc0;
    pc1 = nc1;
  }

  // ---- plain-store partial C: D layout col=lane&15, row=(lane>>4)*4+r ----
  float* pb = partial + (size_t)blockIdx.x * kPix;
#pragma unroll
  for (int mt = 0; mt < 2; ++mt) {
#pragma unroll
    for (int vt = 0; vt < 2; ++vt) {
      const int v = vi * 32 + vt * 16 + l15;
#pragma unroll
      for (int r = 0; r < 4; ++r) {
        const int w = wi * 32 + mt * 16 + l4 * 4 + r;
        if (w < kW && v < kW) pb[w * kW + v] = acc4[mt][vt][r];
      }
    }
  }
}

__global__ __launch_bounds__(256) void reduce_kernel(const float* __restrict__ partial,
                                                     float* __restrict__ out) {
  constexpr int F4 = kPix / 4;          // 900 float4 per image
  int i = blockIdx.x * 256 + threadIdx.x;
  if (i >= kB * F4) return;
  int b = i / F4;
  int j = i - b * F4;
  const float4* p = (const float4*)partial + (size_t)b * KSPLIT * F4 + j;
  float4 s = p[0];
#pragma unroll
  for (int k = 1; k < KSPLIT; ++k) {
    float4 t = p[(size_t)k * F4];
    s.x += t.x; s.y += t.y; s.z += t.z; s.w += t.w;
  }
  float4 r;
  r.x = fminf(s.x, 1.0f);
  r.y = fminf(s.y, 1.0f);
  r.z = fminf(s.z, 1.0f);
  r.w = fminf(s.w, 1.0f);
  ((float4*)out)[i] = r;
}

// Fallback if ws is too small: one block per batch, LDS-atomic splat, direct write.
__global__ __launch_bounds__(1024) void splat_direct_kernel(const float* __restrict__ x,
                                                            float* __restrict__ out) {
  __shared__ float res[kPix];
  const int b = blockIdx.x;
  const int tid = threadIdx.x;
  for (int i = tid; i < kPix; i += 1024) res[i] = 0.0f;
  __syncthreads();
  const float* xb = x + (size_t)b * kL * 8;
  for (int p = tid; p < kL * kN; p += 1024) {
    int l = p / kN;
    int n = p - l * kN;
    float t0 = (float)n * (1.0f / 30.0f);
    float t  = 2.0f * t0 * t0 * t0 - 3.0f * t0 * t0 + 2.0f * t0;
    float t2 = t * t, t3 = t2 * t;
    float B0 = t3, B1 = 3.0f * (t2 - t3), B2 = 3.0f * (t3 - 2.0f * t2 + t);
    float omt = 1.0f - t, B3 = omt * omt * omt;
    const float4* c = (const float4*)(xb + l * 8);
    float4 c0 = c[0], c1 = c[1];
    float X = B0 * c0.x + B1 * c0.z + B2 * c1.x + B3 * c1.z;
    float Y = B0 * c0.y + B1 * c0.w + B2 * c1.y + B3 * c1.w;
    float fx = X * kW, fy = Y * kW;
    int wlo = (int)ceilf(fx - kRadPix), vlo = (int)ceilf(fy - kRadPix);
    for (int i = 0; i < 8; ++i) {
      int w = wlo + i;
      if (w < 0 || w >= kW) continue;
      float dw = ((float)w - fx) * (1.0f / kW);
      float gx = __expf(-dw * dw * kAlphaInv);
      for (int j = 0; j < 8; ++j) {
        int v = vlo + j;
        if (v < 0 || v >= kW) continue;
        float dv = ((float)v - fy) * (1.0f / kW);
        atomicAdd(&res[w * kW + v], gx * __expf(-dv * dv * kAlphaInv));
      }
    }
  }
  __syncthreads();
  float* outb = out + (size_t)b * kPix;
  for (int i = tid; i < kPix; i += 1024) outb[i] = fminf(res[i], 1.0f);
}

extern "C" void kernel_launch(void* const* d_in, const int* in_sizes, int n_in,
                              void* d_out, int out_size, void* d_ws, size_t ws_size,
                              hipStream_t stream) {
  const float* x = (const float*)d_in[0];
  float* out = (float*)d_out;
  const size_t part_bytes = (size_t)kB * KSPLIT * kPix * sizeof(float);

  if (ws_size >= part_bytes) {
    float* partial = (float*)d_ws;
    bezier_gemm_kernel<<<dim3(kB * KSPLIT), dim3(256), 0, stream>>>(x, partial);
    int n4 = kB * kPix / 4;
    reduce_kernel<<<dim3((n4 + 255) / 256), dim3(256), 0, stream>>>(partial, out);
  } else {
    splat_direct_kernel<<<dim3(kB), dim3(1024), 0, stream>>>(x, out);
  }
}

// Round 11
// 24.326 us; speedup vs baseline: 1.2726x; 1.0486x over previous
//
#include <hip/hip_runtime.h>

// Bezier2Image via separable GEMM on matrix cores (R3 base + K-sliced waves):
//   res[b,w,v] = sum_k gX[b,w,k] * gY[b,v,k],  k = (curve, sample)
// Grid = 128 batches x 4 K-split blocks, 256 thr (4 waves), lb(256,2).
// Per 128-col chunk: scatter truncated 8px gaussian windows (f16, padded
// rows, incremental exp2: 2 transcendentals/column) -> barrier -> MFMA.
// K-SLICED: wave wid contracts cols [wid*32,+32) and accumulates the FULL
// 60x64 C (4x4 tiles of 16x16x32) -> every staged byte is ds_read exactly
// once (32 b128/chunk/block vs 64 in the quadrant scheme). Epilogue: 2-slot
// LDS tree-reduce of the 4 per-wave partials, plain partial store; float4
// reduce kernel sums 4 + clamps.

namespace {
constexpr int   kN = 30;            // samples per curve
constexpr int   kW = 60;            // image side
constexpr int   kL = 160;           // curves per batch
constexpr int   kB = 128;           // batch
constexpr float kRadPix = 3.5f;     // truncation radius in pixels
constexpr float kK2 = 2.00374312f;  // (1/alpha)/60^2 * log2(e)
constexpr int   KSPLIT = 4;         // K-split blocks per batch
constexpr int   CPB = kL / KSPLIT;  // 40 curves per block
constexpr int   KC = 128;           // k-chunk (4 curves x 32, 30 used)
constexpr int   NCH = CPB * 32 / KC;  // 10 chunks
constexpr int   LDK = KC + 8;       // padded LDS row length (f16)
constexpr int   kPix = kW * kW;     // 3600
}

using f32x4 = __attribute__((ext_vector_type(4))) float;
using f16x8 = __attribute__((ext_vector_type(8))) _Float16;

__global__ __launch_bounds__(256, 2) void bezier_gemm_kernel(const float* __restrict__ x,
                                                             float* __restrict__ partial) {
  __shared__ _Float16 sh[2][64][LDK];   // 34.8 KB (reused as f32 in epilogue)
  const int b    = blockIdx.x / KSPLIT;
  const int ks   = blockIdx.x % KSPLIT;
  const int tid  = threadIdx.x;
  const int lane = tid & 63;
  const int wid  = tid >> 6;            // wave = 32-col K-slice of each chunk
  const int l15 = lane & 15;
  const int l4  = lane >> 4;

  f32x4 acc4[4][4] = {};                // FULL 60x64 C per wave (64 VGPR)

  const float* xb = x + ((size_t)b * kL + (size_t)ks * CPB) * 8;

  // ---- initial full zero of the staging tile ----
  {
    uint4* shv = (uint4*)&sh[0][0][0];
    constexpr int NZ = 2 * 64 * LDK * 2 / 16;
    for (int i = tid; i < NZ; i += 256) shv[i] = make_uint4(0, 0, 0, 0);
  }

  // ---- per-thread fixed staging role: one (matrix, column) ----
  const int col = tid & 127;            // k-column within chunk (constant)
  const int mat = tid >> 7;             // 0 = gX, 1 = gY       (constant)
  const int n   = col & 31;             // sample index (constant; 30,31 = pad)
  const bool valid = (n < kN);
  float B0, B1, B2, B3;
  {
    float t0 = (float)n * (1.0f / 30.0f);
    float t  = 2.0f * t0 * t0 * t0 - 3.0f * t0 * t0 + 2.0f * t0;
    float t2 = t * t, t3 = t2 * t;
    B0 = t3;
    B1 = 3.0f * (t2 - t3);
    B2 = 3.0f * (t3 - 2.0f * t2 + t);
    float omt = 1.0f - t;
    B3 = omt * omt * omt;
  }
  // gaussian tail table C_i = 2^(-K2*i*i)
  const float C1 = 0.2493521f,    C2 = 3.8659230e-3f, C3 = 3.7266550e-6f,
              C4 = 2.2336300e-10f, C5 = 8.3239000e-16f, C6 = 1.9287500e-22f,
              C7 = 2.7787500e-31f;
  int lo_prev = 0;                      // rows 0..7 start zeroed; re-zero harmless

  __syncthreads();                      // initial zero visible to all

  for (int ch = 0; ch < NCH; ++ch) {
    // ---- scatter: zero own old window, write own new window (column-exclusive)
    if (valid) {
      const int lc = ch * 4 + (col >> 5);
      const float4* c = (const float4*)(xb + lc * 8);
      float4 c0 = c[0], c1 = c[1];
      float P = mat ? (B0 * c0.y + B1 * c0.w + B2 * c1.y + B3 * c1.w)
                    : (B0 * c0.x + B1 * c0.z + B2 * c1.x + B3 * c1.z);
      float fp = P * 60.0f;             // pixel-space center, in [0,60]
      int lo = (int)ceilf(fp - kRadPix);
#pragma unroll
      for (int i = 0; i < 8; ++i) {
        int m = lo_prev + i;
        if (m >= 0 && m < kW) sh[mat][m][col] = (_Float16)0.0f;
      }
      // incremental gaussian: e_i = E0 * R^i * C_i = 2^(-K2*(u+i)^2)
      float u  = (float)lo - fp;        // in [-3.5, -2.5)
      float E0 = __builtin_amdgcn_exp2f(-kK2 * u * u);
      float R  = __builtin_amdgcn_exp2f(-2.0f * kK2 * u);
      float p1 = E0 * R, p2 = p1 * R, p3 = p2 * R, p4 = p3 * R,
            p5 = p4 * R, p6 = p5 * R, p7 = p6 * R;
      float e[8] = {E0, p1 * C1, p2 * C2, p3 * C3, p4 * C4, p5 * C5, p6 * C6, p7 * C7};
#pragma unroll
      for (int i = 0; i < 8; ++i) {
        int m = lo + i;
        if (m >= 0 && m < kW) sh[mat][m][col] = (_Float16)e[i];
      }
      lo_prev = lo;
    }
    __syncthreads();

    // ---- MFMA: wave wid contracts its 32-col K-slice into full 60x64 C ----
    {
      const int ke = wid * 32 + l4 * 8;
      f16x8 af[4], bf[4];
#pragma unroll
      for (int mt = 0; mt < 4; ++mt) af[mt] = *(const f16x8*)&sh[0][mt * 16 + l15][ke];
#pragma unroll
      for (int vt = 0; vt < 4; ++vt) bf[vt] = *(const f16x8*)&sh[1][vt * 16 + l15][ke];
#pragma unroll
      for (int mt = 0; mt < 4; ++mt)
#pragma unroll
        for (int vt = 0; vt < 4; ++vt)
          acc4[mt][vt] = __builtin_amdgcn_mfma_f32_16x16x32_f16(af[mt], bf[vt],
                                                                acc4[mt][vt], 0, 0, 0);
    }
    __syncthreads();   // MFMA reads done before next chunk's scatter overwrites
  }

  // ---- epilogue: tree-reduce 4 wave partials (2 slots of 64x64 f32 in LDS) ----
  // C layout per 16x16 tile: col = l15, row = l4*4 + r   (m89-verified)
  float* red = (float*)sh;              // 8704 f32 available, use 2x4096
  if (wid < 2) {
    float* slot = red + wid * 4096;
#pragma unroll
    for (int mt = 0; mt < 4; ++mt)
#pragma unroll
      for (int vt = 0; vt < 4; ++vt)
#pragma unroll
        for (int r = 0; r < 4; ++r)
          slot[(mt * 16 + l4 * 4 + r) * 64 + vt * 16 + l15] = acc4[mt][vt][r];
  }
  __syncthreads();
  if (wid >= 2) {
    float* slot = red + (wid - 2) * 4096;
#pragma unroll
    for (int mt = 0; mt < 4; ++mt)
#pragma unroll
      for (int vt = 0; vt < 4; ++vt)
#pragma unroll
        for (int r = 0; r < 4; ++r)
          slot[(mt * 16 + l4 * 4 + r) * 64 + vt * 16 + l15] += acc4[mt][vt][r];
  }
  __syncthreads();

  float* pb = partial + (size_t)blockIdx.x * kPix;
  for (int p = tid; p < kPix; p += 256) {
    int r = p / kW;
    int c = p - r * kW;
    int idx = r * 64 + c;
    pb[p] = red[idx] + red[4096 + idx];
  }
}

__global__ __launch_bounds__(256) void reduce_kernel(const float* __restrict__ partial,
                                                     float* __restrict__ out) {
  constexpr int F4 = kPix / 4;          // 900 float4 per image
  int i = blockIdx.x * 256 + threadIdx.x;
  if (i >= kB * F4) return;
  int b = i / F4;
  int j = i - b * F4;
  const float4* p = (const float4*)partial + (size_t)b * KSPLIT * F4 + j;
  float4 s0 = p[0], s1 = p[F4], s2 = p[2 * F4], s3 = p[3 * F4];
  float4 r;
  r.x = fminf(s0.x + s1.x + s2.x + s3.x, 1.0f);
  r.y = fminf(s0.y + s1.y + s2.y + s3.y, 1.0f);
  r.z = fminf(s0.z + s1.z + s2.z + s3.z, 1.0f);
  r.w = fminf(s0.w + s1.w + s2.w + s3.w, 1.0f);
  ((float4*)out)[i] = r;
}

// Fallback if ws is too small: one block per batch, LDS-atomic splat, direct write.
__global__ __launch_bounds__(1024) void splat_direct_kernel(const float* __restrict__ x,
                                                            float* __restrict__ out) {
  __shared__ float res[kPix];
  const int b = blockIdx.x;
  const int tid = threadIdx.x;
  for (int i = tid; i < kPix; i += 1024) res[i] = 0.0f;
  __syncthreads();
  const float* xb = x + (size_t)b * kL * 8;
  for (int p = tid; p < kL * kN; p += 1024) {
    int l = p / kN;
    int n = p - l * kN;
    float t0 = (float)n * (1.0f / 30.0f);
    float t  = 2.0f * t0 * t0 * t0 - 3.0f * t0 * t0 + 2.0f * t0;
    float t2 = t * t, t3 = t2 * t;
    float B0 = t3, B1 = 3.0f * (t2 - t3), B2 = 3.0f * (t3 - 2.0f * t2 + t);
    float omt = 1.0f - t, B3 = omt * omt * omt;
    const float4* c = (const float4*)(xb + l * 8);
    float4 c0 = c[0], c1 = c[1];
    float X = B0 * c0.x + B1 * c0.z + B2 * c1.x + B3 * c1.z;
    float Y = B0 * c0.y + B1 * c0.w + B2 * c1.y + B3 * c1.w;
    float fx = X * kW, fy = Y * kW;
    int wlo = (int)ceilf(fx - kRadPix), vlo = (int)ceilf(fy - kRadPix);
    for (int i = 0; i < 8; ++i) {
      int w = wlo + i;
      if (w < 0 || w >= kW) continue;
      float dw = ((float)w - fx) * (1.0f / kW);
      float gx = __expf(-dw * dw * 5000.0f);
      for (int j = 0; j < 8; ++j) {
        int v = vlo + j;
        if (v < 0 || v >= kW) continue;
        float dv = ((float)v - fy) * (1.0f / kW);
        atomicAdd(&res[w * kW + v], gx * __expf(-dv * dv * 5000.0f));
      }
    }
  }
  __syncthreads();
  float* outb = out + (size_t)b * kPix;
  for (int i = tid; i < kPix; i += 1024) outb[i] = fminf(res[i], 1.0f);
}

extern "C" void kernel_launch(void* const* d_in, const int* in_sizes, int n_in,
                              void* d_out, int out_size, void* d_ws, size_t ws_size,
                              hipStream_t stream) {
  const float* x = (const float*)d_in[0];
  float* out = (float*)d_out;
  const size_t part_bytes = (size_t)kB * KSPLIT * kPix * sizeof(float);

  if (ws_size >= part_bytes) {
    float* partial = (float*)d_ws;
    bezier_gemm_kernel<<<dim3(kB * KSPLIT), dim3(256), 0, stream>>>(x, partial);
    int n4 = kB * kPix / 4;
    reduce_kernel<<<dim3((n4 + 255) / 256), dim3(256), 0, stream>>>(partial, out);
  } else {
    splat_direct_kernel<<<dim3(kB), dim3(1024), 0, stream>>>(x, out);
  }
}